// Round 5
// baseline (412.396 us; speedup 1.0000x reference)
//
#include <hip/hip_runtime.h>
#include <hip/hip_cooperative_groups.h>

namespace cg = cooperative_groups;

#define N_NODES_C 100000
#define N_EDGES_C 1600000
#define D_C 128
#define NBKT 1563        // ceil(100000/64) buckets of 64 rows
#define RPB 64           // rows per bucket (shift-based bucketing)
#define CAP 1536         // per-bucket edge capacity (mean 1024, sigma 32 -> +16 sigma)
#define CAP_H 768        // per-half-bucket capacity
#define PTILE 2048       // edges per partition item (2048 -> smaller LDS union)
#define NPB ((N_EDGES_C + PTILE - 1) / PTILE)     // 782 partition items
#define NGB ((N_NODES_C + 63) / 64)               // 1563 gemm items
#define WB_STRIDE 136    // padded row stride (elems) for LDS tiles

// bf16 helpers (manual RNE pack; unpack is exact)
static __device__ __forceinline__ unsigned short f2bf(float x) {
    unsigned u = __float_as_uint(x);
    unsigned r = 0x7fffu + ((u >> 16) & 1u);
    return (unsigned short)((u + r) >> 16);
}
static __device__ __forceinline__ float bflo(unsigned u) { return __uint_as_float(u << 16); }
static __device__ __forceinline__ float bfhi(unsigned u) { return __uint_as_float(u & 0xffff0000u); }

typedef __attribute__((ext_vector_type(8))) __bf16 bf16x8;
typedef __attribute__((ext_vector_type(4))) float f32x4;
union FragU { uint4 u; bf16x8 b; };

// Shared-memory union across all roles: 20,696 B -> 7 blocks/CU.
union SMemAll {
    struct {
        int lhist[NBKT];
        int lbase[NBKT];
        unsigned short ebkt[PTILE];
        unsigned short ernk[PTILE];
    } part;                                   // 20,696 B
    unsigned short ytile[4][16 * WB_STRIDE];  // 17,408 B
    struct {
        int2 pl[CAP_H];                       // 6,144 B
        int hist[32];
        int lcur[32];
        int rb[32];
        int rc[32];
    } agg;                                    // 6,656 B
};

// ---------------------------------------------------------------------------
// Role bodies (shared by cooperative kernel and fallback kernels)
// ---------------------------------------------------------------------------
static __device__ __forceinline__ void partition_item(SMemAll& sm, int item,
        const int* __restrict__ rows, const int* __restrict__ cols,
        const float* __restrict__ vals, int* __restrict__ gcount,
        int2* __restrict__ staging, int E) {
    const int tid = threadIdx.x;
    const int t0 = item * PTILE;

    for (int i = tid; i < NBKT; i += 256) sm.part.lhist[i] = 0;
    __syncthreads();

#pragma unroll
    for (int k = 0; k < PTILE / 256; ++k) {
        int e = t0 + k * 256 + tid;
        if (e < E) {
            int bkt = rows[e] >> 6;
            int rnk = atomicAdd(&sm.part.lhist[bkt], 1);
            sm.part.ebkt[k * 256 + tid] = (unsigned short)bkt;
            sm.part.ernk[k * 256 + tid] = (unsigned short)rnk;
        }
    }
    __syncthreads();

    for (int i = tid; i < NBKT; i += 256)
        sm.part.lbase[i] = sm.part.lhist[i] ? atomicAdd(&gcount[i], sm.part.lhist[i]) : 0;
    __syncthreads();

#pragma unroll
    for (int k = 0; k < PTILE / 256; ++k) {
        int e = t0 + k * 256 + tid;
        if (e < E) {
            int li = k * 256 + tid;
            int bkt = sm.part.ebkt[li];
            int dst = sm.part.lbase[bkt] + sm.part.ernk[li];
            if (dst < CAP) {
                int rl = rows[e] & (RPB - 1);
                int2 p;
                p.x = cols[e] | (rl << 17);
                p.y = __float_as_int(vals[e]);
                staging[(long)bkt * CAP + dst] = p;
            }
        }
    }
}

static __device__ __forceinline__ void gemm_item(SMemAll& sm, int g,
        const float* __restrict__ X, const unsigned short* __restrict__ Wbf,
        unsigned short* __restrict__ Y, int n) {
    const int tid = threadIdx.x;
    const int wave = tid >> 6;
    const int lane = tid & 63;
    const int m16 = lane & 15;
    const int quad = lane >> 4;

    const int row0 = g * 64 + wave * 16;
    int row = row0 + m16;
    int rowc = (row < n) ? row : (n - 1);

    FragU a[4];
    const float* xp = X + (long)rowc * D_C + quad * 8;
#pragma unroll
    for (int s = 0; s < 4; ++s) {
        float4 x0 = *(const float4*)(xp + s * 32);
        float4 x1 = *(const float4*)(xp + s * 32 + 4);
        a[s].u.x = (unsigned)f2bf(x0.x) | ((unsigned)f2bf(x0.y) << 16);
        a[s].u.y = (unsigned)f2bf(x0.z) | ((unsigned)f2bf(x0.w) << 16);
        a[s].u.z = (unsigned)f2bf(x1.x) | ((unsigned)f2bf(x1.y) << 16);
        a[s].u.w = (unsigned)f2bf(x1.z) | ((unsigned)f2bf(x1.w) << 16);
    }

    f32x4 acc[8];
#pragma unroll
    for (int t = 0; t < 8; ++t) acc[t] = (f32x4){0.f, 0.f, 0.f, 0.f};

#pragma unroll
    for (int s = 0; s < 4; ++s) {
#pragma unroll
        for (int t = 0; t < 8; ++t) {
            FragU bf;
            bf.u = *(const uint4*)&Wbf[(t * 16 + m16) * D_C + s * 32 + quad * 8];
            acc[t] = __builtin_amdgcn_mfma_f32_16x16x32_bf16(a[s].b, bf.b, acc[t], 0, 0, 0);
        }
    }

    unsigned short* yt = sm.ytile[wave];
#pragma unroll
    for (int t = 0; t < 8; ++t)
#pragma unroll
        for (int r = 0; r < 4; ++r)
            yt[(quad * 4 + r) * WB_STRIDE + t * 16 + m16] = f2bf(acc[t][r]);
    __syncthreads();

    // each lane moves 16 elems (2 x uint4); 8 lanes cover a 128-elem row
#pragma unroll
    for (int h = 0; h < 2; ++h) {
        int row_l = h * 8 + (lane >> 3);
        int orow = row0 + row_l;
        if (orow < n) {
            const unsigned short* src = &yt[row_l * WB_STRIDE + (lane & 7) * 16];
            uint4 v0 = *(const uint4*)(src);
            uint4 v1 = *(const uint4*)(src + 8);
            uint4* dst = (uint4*)&Y[(long)orow * D_C + (lane & 7) * 16];
            dst[0] = v0;
            dst[1] = v1;
        }
    }
}

static __device__ __forceinline__ void agg_item(SMemAll& sm, int item,
        const int* __restrict__ gcount, const int2* __restrict__ staging,
        const unsigned short* __restrict__ Y, const float* __restrict__ bias,
        float* __restrict__ out, int n) {
    const int bb = item >> 1;
    const int half = item & 1;
    const int tid = threadIdx.x;
    int cnt = gcount[bb];
    if (cnt > CAP) cnt = CAP;
    const long s = (long)bb * CAP;

    if (tid < 32) sm.agg.hist[tid] = 0;
    __syncthreads();

    const unsigned* sx = (const unsigned*)(staging + s);  // .x words at even idx
    for (int i = tid; i < cnt; i += 256) {
        int rl = sx[2 * i] >> 17;
        if ((rl >> 5) == half) atomicAdd(&sm.agg.hist[rl & 31], 1);
    }
    __syncthreads();

    int v = (tid < 32) ? sm.agg.hist[tid] : 0;
    for (int off = 1; off < 32; off <<= 1) {
        int t = (tid >= off && tid < 32) ? sm.agg.hist[tid - off] : 0;
        __syncthreads();
        if (tid < 32) sm.agg.hist[tid] += t;
        __syncthreads();
    }
    if (tid < 32) {
        int excl = sm.agg.hist[tid] - v;
        sm.agg.lcur[tid] = excl;
        sm.agg.rb[tid] = excl;
        sm.agg.rc[tid] = v;
    }
    __syncthreads();

    for (int i = tid; i < cnt; i += 256) {
        int2 p = staging[s + i];
        int rl = ((unsigned)p.x) >> 17;
        if ((rl >> 5) == half) {
            int slot = atomicAdd(&sm.agg.lcur[rl & 31], 1);
            if (slot < CAP_H) sm.agg.pl[slot] = p;
        }
    }
    __syncthreads();

    const int lane = tid & 15;
    const unsigned short* Yl = Y + lane * 8;
    float4 b0 = *(const float4*)&bias[lane * 8];
    float4 b1 = *(const float4*)&bias[lane * 8 + 4];

#pragma unroll
    for (int pass = 0; pass < 2; ++pass) {
        int rlocal = pass * 16 + (tid >> 4);
        int row = bb * RPB + half * 32 + rlocal;
        if (row >= n) continue;

        int i = sm.agg.rb[rlocal];
        int e = i + sm.agg.rc[rlocal];
        if (e > CAP_H) e = CAP_H;

        float acc[8];
        acc[0] = b0.x; acc[1] = b0.y; acc[2] = b0.z; acc[3] = b0.w;
        acc[4] = b1.x; acc[5] = b1.y; acc[6] = b1.z; acc[7] = b1.w;

        for (; i + 8 <= e; i += 8) {  // 8 independent 256B gathers in flight
            int2 p[8];
            uint4 y[8];
#pragma unroll
            for (int u = 0; u < 8; ++u) p[u] = sm.agg.pl[i + u];
#pragma unroll
            for (int u = 0; u < 8; ++u)
                y[u] = *(const uint4*)&Yl[(long)(p[u].x & 0x1FFFF) * D_C];
#pragma unroll
            for (int u = 0; u < 8; ++u) {
                float v2 = __int_as_float(p[u].y);
                acc[0] += v2 * bflo(y[u].x); acc[1] += v2 * bfhi(y[u].x);
                acc[2] += v2 * bflo(y[u].y); acc[3] += v2 * bfhi(y[u].y);
                acc[4] += v2 * bflo(y[u].z); acc[5] += v2 * bfhi(y[u].z);
                acc[6] += v2 * bflo(y[u].w); acc[7] += v2 * bfhi(y[u].w);
            }
        }
        for (; i + 4 <= e; i += 4) {
            int2 p[4];
            uint4 y[4];
#pragma unroll
            for (int u = 0; u < 4; ++u) p[u] = sm.agg.pl[i + u];
#pragma unroll
            for (int u = 0; u < 4; ++u)
                y[u] = *(const uint4*)&Yl[(long)(p[u].x & 0x1FFFF) * D_C];
#pragma unroll
            for (int u = 0; u < 4; ++u) {
                float v2 = __int_as_float(p[u].y);
                acc[0] += v2 * bflo(y[u].x); acc[1] += v2 * bfhi(y[u].x);
                acc[2] += v2 * bflo(y[u].y); acc[3] += v2 * bfhi(y[u].y);
                acc[4] += v2 * bflo(y[u].z); acc[5] += v2 * bfhi(y[u].z);
                acc[6] += v2 * bflo(y[u].w); acc[7] += v2 * bfhi(y[u].w);
            }
        }
        for (; i < e; ++i) {
            int2 p = sm.agg.pl[i];
            uint4 y = *(const uint4*)&Yl[(long)(p.x & 0x1FFFF) * D_C];
            float v2 = __int_as_float(p.y);
            acc[0] += v2 * bflo(y.x); acc[1] += v2 * bfhi(y.x);
            acc[2] += v2 * bflo(y.y); acc[3] += v2 * bfhi(y.y);
            acc[4] += v2 * bflo(y.z); acc[5] += v2 * bfhi(y.z);
            acc[6] += v2 * bflo(y.w); acc[7] += v2 * bfhi(y.w);
        }

        f32x4 o0 = {acc[0], acc[1], acc[2], acc[3]};
        f32x4 o1 = {acc[4], acc[5], acc[6], acc[7]};
        f32x4* op = (f32x4*)&out[(long)row * D_C + lane * 8];
        // out is write-once dead data: keep it out of L2/L3 so Y stays hot
        __builtin_nontemporal_store(o0, op);
        __builtin_nontemporal_store(o1, op + 1);
    }
}

// ---------------------------------------------------------------------------
// Cooperative single-dispatch kernel: phase0 (W->bf16 + gcount=0), sync,
// phaseA (partition || gemm), sync, phaseB (sort+aggregate). Persistent
// blocks; grid sized to co-residency by the occupancy API.
// ---------------------------------------------------------------------------
__global__ __launch_bounds__(256) void fused_all(const float* __restrict__ X,
                                                 const int* __restrict__ rows,
                                                 const int* __restrict__ cols,
                                                 const float* __restrict__ vals,
                                                 const float* __restrict__ W,
                                                 const float* __restrict__ bias,
                                                 unsigned short* __restrict__ Wbf,
                                                 int* __restrict__ gcount,
                                                 int2* __restrict__ staging,
                                                 unsigned short* __restrict__ Y,
                                                 float* __restrict__ out,
                                                 int n, int E) {
    __shared__ SMemAll sm;
    cg::grid_group grid = cg::this_grid();
    const int nb = gridDim.x;

    // phase 0: convert W (4096 float4) + zero gcount
    for (int t = blockIdx.x * 256 + threadIdx.x; t < 4096 + NBKT; t += nb * 256) {
        if (t < 4096) {
            float4 w = ((const float4*)W)[t];
            uint2 p;
            p.x = (unsigned)f2bf(w.x) | ((unsigned)f2bf(w.y) << 16);
            p.y = (unsigned)f2bf(w.z) | ((unsigned)f2bf(w.w) << 16);
            ((uint2*)Wbf)[t] = p;
        } else {
            gcount[t - 4096] = 0;
        }
    }
    __threadfence();
    grid.sync();

    // phase A: 782 partition items + 1563 gemm items
    for (int item = blockIdx.x; item < NPB + NGB; item += nb) {
        __syncthreads();
        if (item < NPB)
            partition_item(sm, item, rows, cols, vals, gcount, staging, E);
        else
            gemm_item(sm, item - NPB, X, Wbf, Y, n);
    }
    __threadfence();
    grid.sync();

    // phase B: 3126 half-bucket sort+aggregate items
    for (int item = blockIdx.x; item < 2 * NBKT; item += nb) {
        __syncthreads();
        agg_item(sm, item, gcount, staging, Y, bias, out, n);
    }
}

// ---------------------------------------------------------------------------
// Fallback 1 (no cooperative launch): round-4 3-kernel path (proven, 242 us).
// ---------------------------------------------------------------------------
__global__ __launch_bounds__(256) void prep(const float* __restrict__ W,
                                            unsigned short* __restrict__ Wbf,
                                            int* __restrict__ gcount) {
    int t = blockIdx.x * 256 + threadIdx.x;
    if (t < 4096) {
        float4 w = ((const float4*)W)[t];
        uint2 p;
        p.x = (unsigned)f2bf(w.x) | ((unsigned)f2bf(w.y) << 16);
        p.y = (unsigned)f2bf(w.z) | ((unsigned)f2bf(w.w) << 16);
        ((uint2*)Wbf)[t] = p;
    } else {
        int j = t - 4096;
        if (j < NBKT) gcount[j] = 0;
    }
}

__global__ __launch_bounds__(256) void fused(const float* __restrict__ X,
                                             const int* __restrict__ rows,
                                             const int* __restrict__ cols,
                                             const float* __restrict__ vals,
                                             const unsigned short* __restrict__ Wbf,
                                             int* __restrict__ gcount,
                                             int2* __restrict__ staging,
                                             unsigned short* __restrict__ Y,
                                             int n, int E) {
    __shared__ SMemAll sm;
    if (blockIdx.x < NPB)
        partition_item(sm, blockIdx.x, rows, cols, vals, gcount, staging, E);
    else
        gemm_item(sm, blockIdx.x - NPB, X, Wbf, Y, n);
}

__global__ __launch_bounds__(256) void sort_aggregate(const int* __restrict__ gcount,
                                                      const int2* __restrict__ staging,
                                                      const unsigned short* __restrict__ Y,
                                                      const float* __restrict__ bias,
                                                      float* __restrict__ out, int n) {
    __shared__ SMemAll sm;
    agg_item(sm, blockIdx.x, gcount, staging, Y, bias, out, n);
}

// ---------------------------------------------------------------------------
// Fallback 2 (ws too small): standalone gemm + atomic scatter.
// ---------------------------------------------------------------------------
__global__ __launch_bounds__(256) void gemm_mfma(const float* __restrict__ X,
                                                 const float* __restrict__ W,
                                                 unsigned short* __restrict__ Y, int n) {
    __shared__ unsigned short Wb[128 * WB_STRIDE];

    const int tid = threadIdx.x;
    const int wave = tid >> 6;
    const int lane = tid & 63;
    const int m16 = lane & 15;
    const int quad = lane >> 4;

    const int row0 = blockIdx.x * 64 + wave * 16;
    int row = row0 + m16;
    int rowc = (row < n) ? row : (n - 1);

    float4 xv[4][2];
    const float* xp = X + (long)rowc * D_C + quad * 8;
#pragma unroll
    for (int s = 0; s < 4; ++s) {
        xv[s][0] = *(const float4*)(xp + s * 32);
        xv[s][1] = *(const float4*)(xp + s * 32 + 4);
    }

    for (int i = tid; i < 128 * 32; i += 256) {
        int o = i >> 5;
        int k4 = (i & 31) * 4;
        float4 w = *(const float4*)&W[o * 128 + k4];
        uint2 p;
        p.x = (unsigned)f2bf(w.x) | ((unsigned)f2bf(w.y) << 16);
        p.y = (unsigned)f2bf(w.z) | ((unsigned)f2bf(w.w) << 16);
        *(uint2*)&Wb[o * WB_STRIDE + k4] = p;
    }
    __syncthreads();

    FragU a[4];
#pragma unroll
    for (int s = 0; s < 4; ++s) {
        a[s].u.x = (unsigned)f2bf(xv[s][0].x) | ((unsigned)f2bf(xv[s][0].y) << 16);
        a[s].u.y = (unsigned)f2bf(xv[s][0].z) | ((unsigned)f2bf(xv[s][0].w) << 16);
        a[s].u.z = (unsigned)f2bf(xv[s][1].x) | ((unsigned)f2bf(xv[s][1].y) << 16);
        a[s].u.w = (unsigned)f2bf(xv[s][1].z) | ((unsigned)f2bf(xv[s][1].w) << 16);
    }

    f32x4 acc[8];
#pragma unroll
    for (int t = 0; t < 8; ++t) acc[t] = (f32x4){0.f, 0.f, 0.f, 0.f};

#pragma unroll
    for (int s = 0; s < 4; ++s) {
#pragma unroll
        for (int t = 0; t < 8; ++t) {
            FragU bf;
            bf.u = *(const uint4*)&Wb[(t * 16 + m16) * WB_STRIDE + s * 32 + quad * 8];
            acc[t] = __builtin_amdgcn_mfma_f32_16x16x32_bf16(a[s].b, bf.b, acc[t], 0, 0, 0);
        }
    }

#pragma unroll
    for (int t = 0; t < 8; ++t) {
#pragma unroll
        for (int r = 0; r < 4; ++r) {
            int orow = row0 + quad * 4 + r;
            if (orow < n) Y[(long)orow * D_C + t * 16 + m16] = f2bf(acc[t][r]);
        }
    }
}

__global__ __launch_bounds__(256) void init_out(const float* __restrict__ b,
                                                float* __restrict__ out, int n) {
    int idx = blockIdx.x * 256 + threadIdx.x;
    int total = n * (D_C / 4);
    if (idx < total) {
        int o4 = idx & (D_C / 4 - 1);
        ((float4*)out)[idx] = ((const float4*)b)[o4];
    }
}

__global__ __launch_bounds__(256) void scatter_edges(const int* __restrict__ rows,
                                                     const int* __restrict__ cols,
                                                     const float* __restrict__ vals,
                                                     const unsigned short* __restrict__ Y,
                                                     float* __restrict__ out, int E) {
    int e = blockIdx.x * 8 + (threadIdx.x >> 5);
    if (e >= E) return;
    int lane = threadIdx.x & 31;
    int row = rows[e];
    int col = cols[e];
    float v = vals[e];
    uint2 y = *(const uint2*)&Y[(long)col * D_C + lane * 4];
    float* dst = out + (long)row * D_C + lane * 4;
    unsafeAtomicAdd(dst + 0, v * bflo(y.x));
    unsafeAtomicAdd(dst + 1, v * bfhi(y.x));
    unsafeAtomicAdd(dst + 2, v * bflo(y.y));
    unsafeAtomicAdd(dst + 3, v * bfhi(y.y));
}

extern "C" void kernel_launch(void* const* d_in, const int* in_sizes, int n_in,
                              void* d_out, int out_size, void* d_ws, size_t ws_size,
                              hipStream_t stream) {
    const float* X  = (const float*)d_in[0];
    const int*   Ar = (const int*)d_in[1];
    const int*   Ac = (const int*)d_in[2];
    const float* Av = (const float*)d_in[3];
    const float* W  = (const float*)d_in[4];
    const float* b  = (const float*)d_in[5];
    float* out = (float*)d_out;

    // Workspace layout:
    unsigned short* Y = (unsigned short*)d_ws;              // 25.6 MB
    int2* staging = (int2*)(Y + 12800000);                  // 19.2 MB
    unsigned short* Wbf = (unsigned short*)(staging + (size_t)NBKT * CAP);  // 32 KB
    int* gcount = (int*)(Wbf + 16384);                      // 6.25 KB
    size_t need = (size_t)12800000 * 2 + (size_t)NBKT * CAP * 8 + 32768 + (size_t)NBKT * 4;

    // One-time co-residency sizing for the cooperative path (host-only queries).
    static int coopGrid = -2;
    if (coopGrid == -2) {
        coopGrid = 0;
        hipDeviceProp_t prop;
        if (hipGetDeviceProperties(&prop, 0) == hipSuccess && prop.cooperativeLaunch) {
            int maxB = 0;
            if (hipOccupancyMaxActiveBlocksPerMultiprocessor(&maxB, fused_all, 256, 0)
                    == hipSuccess && maxB > 0)
                coopGrid = maxB * prop.multiProcessorCount;
        }
    }

    if (ws_size >= need && coopGrid > 0) {
        const float* X_ = X; const int* Ar_ = Ar; const int* Ac_ = Ac;
        const float* Av_ = Av; const float* W_ = W; const float* b_ = b;
        unsigned short* Wbf_ = Wbf; int* gcount_ = gcount; int2* staging_ = staging;
        unsigned short* Y_ = Y; float* out_ = out;
        int n_ = N_NODES_C, E_ = N_EDGES_C;
        void* args[] = {(void*)&X_, (void*)&Ar_, (void*)&Ac_, (void*)&Av_,
                        (void*)&W_, (void*)&b_, (void*)&Wbf_, (void*)&gcount_,
                        (void*)&staging_, (void*)&Y_, (void*)&out_,
                        (void*)&n_, (void*)&E_};
        hipError_t err = hipLaunchCooperativeKernel((const void*)fused_all,
                                                    dim3(coopGrid), dim3(256),
                                                    args, 0, stream);
        if (err == hipSuccess) return;
        coopGrid = 0;  // cooperative launch rejected: use fallback from now on
    }

    if (ws_size >= need) {
        // Fallback 1: round-4 3-kernel path
        prep<<<23, 256, 0, stream>>>(W, Wbf, gcount);
        fused<<<NPB + NGB, 256, 0, stream>>>(X, Ar, Ac, Av, Wbf, gcount, staging, Y,
                                             N_NODES_C, N_EDGES_C);
        sort_aggregate<<<2 * NBKT, 256, 0, stream>>>(gcount, staging, Y, b, out, N_NODES_C);
    } else {
        // Fallback 2: atomic scatter
        gemm_mfma<<<(N_NODES_C + 63) / 64, 256, 0, stream>>>(X, W, Y, N_NODES_C);
        init_out<<<(N_NODES_C * (D_C / 4) + 255) / 256, 256, 0, stream>>>(b, out, N_NODES_C);
        scatter_edges<<<(N_EDGES_C + 7) / 8, 256, 0, stream>>>(Ar, Ac, Av, Y, out, N_EDGES_C);
    }
}

// Round 7
// 226.077 us; speedup vs baseline: 1.8241x; 1.8241x over previous
//
#include <hip/hip_runtime.h>

#define N_NODES_C 100000
#define N_EDGES_C 1600000
#define D_C 128
#define NBKT 1563        // ceil(100000/64) buckets of 64 rows
#define RPB 64           // rows per bucket (shift-based bucketing)
#define CAP 1536         // per-bucket edge capacity (mean 1024, sigma 32 -> +16 sigma)
#define PTILE 4096       // edges per partition block
#define NPB ((N_EDGES_C + PTILE - 1) / PTILE)     // 391 partition blocks
#define NGB ((N_NODES_C + 63) / 64)               // 1563 gemm blocks
#define WB_STRIDE 136    // padded row stride (elems) for LDS tiles

// bf16 helpers (manual RNE pack; unpack is exact)
static __device__ __forceinline__ unsigned short f2bf(float x) {
    unsigned u = __float_as_uint(x);
    unsigned r = 0x7fffu + ((u >> 16) & 1u);
    return (unsigned short)((u + r) >> 16);
}
static __device__ __forceinline__ float bflo(unsigned u) { return __uint_as_float(u << 16); }
static __device__ __forceinline__ float bfhi(unsigned u) { return __uint_as_float(u & 0xffff0000u); }

typedef __attribute__((ext_vector_type(8))) __bf16 bf16x8;
typedef __attribute__((ext_vector_type(4))) float f32x4;
union FragU { uint4 u; bf16x8 b; };

// ---------------------------------------------------------------------------
// K0 (prep): W f32 -> bf16 once (16384 elems), and zero gcount.
// ---------------------------------------------------------------------------
__global__ __launch_bounds__(256) void prep(const float* __restrict__ W,
                                            unsigned short* __restrict__ Wbf,
                                            int* __restrict__ gcount) {
    int t = blockIdx.x * 256 + threadIdx.x;
    if (t < 4096) {
        float4 w = ((const float4*)W)[t];
        uint2 p;
        p.x = (unsigned)f2bf(w.x) | ((unsigned)f2bf(w.y) << 16);
        p.y = (unsigned)f2bf(w.z) | ((unsigned)f2bf(w.w) << 16);
        ((uint2*)Wbf)[t] = p;
    } else {
        int j = t - 4096;
        if (j < NBKT) gcount[j] = 0;
    }
}

// ---------------------------------------------------------------------------
// K1 (fused): role-split grid. blockIdx < NPB -> edge partition (memory-bound);
// else -> GEMM tile (MFMA/VALU-bound). Roles co-resident on CUs -> overlap.
//
// GEMM role: Y = bf16(X @ W^T), 64 rows/block, 16 rows/wave.
//   - Wbf (preconverted bf16) staged once into LDS via uint4 copies.
//     NOTE: uint4 = 16 B = 8 bf16 elems -> a 128-elem row needs 16 uint4
//     copies (round-6 bug: 8 copies staged only half the tile -> NaN).
//   - Same LDS buffer reused after a sync as the Y-transpose tile -> coalesced
//     uint4 stores (each lane moves 16 elems = 2 x uint4 per row-half).
// Partition role: identical algorithm to round-4.
// ---------------------------------------------------------------------------
union SMemF {
    struct {
        int lhist[NBKT];
        int lbase[NBKT];
        unsigned short ebkt[PTILE];
        unsigned short ernk[PTILE];
    } part;                              // 28,888 B
    unsigned short wb[128 * WB_STRIDE];  // 34,816 B (W tile, then Y transpose tile)
};

__global__ __launch_bounds__(256) void fused(const float* __restrict__ X,
                                             const int* __restrict__ rows,
                                             const int* __restrict__ cols,
                                             const float* __restrict__ vals,
                                             const unsigned short* __restrict__ Wbf,
                                             int* __restrict__ gcount,
                                             int2* __restrict__ staging,
                                             unsigned short* __restrict__ Y,
                                             int n, int E) {
    __shared__ SMemF sm;
    const int tid = threadIdx.x;

    if (blockIdx.x < NPB) {
        // ----------------- partition role -----------------
        const int t0 = blockIdx.x * PTILE;

        for (int i = tid; i < NBKT; i += 256) sm.part.lhist[i] = 0;
        __syncthreads();

#pragma unroll
        for (int k = 0; k < PTILE / 256; ++k) {
            int e = t0 + k * 256 + tid;
            if (e < E) {
                int bkt = rows[e] >> 6;
                int rnk = atomicAdd(&sm.part.lhist[bkt], 1);
                sm.part.ebkt[k * 256 + tid] = (unsigned short)bkt;
                sm.part.ernk[k * 256 + tid] = (unsigned short)rnk;
            }
        }
        __syncthreads();

        for (int i = tid; i < NBKT; i += 256)
            sm.part.lbase[i] = sm.part.lhist[i] ? atomicAdd(&gcount[i], sm.part.lhist[i]) : 0;
        __syncthreads();

#pragma unroll
        for (int k = 0; k < PTILE / 256; ++k) {
            int e = t0 + k * 256 + tid;
            if (e < E) {
                int li = k * 256 + tid;
                int bkt = sm.part.ebkt[li];
                int dst = sm.part.lbase[bkt] + sm.part.ernk[li];
                if (dst < CAP) {
                    int rl = rows[e] & (RPB - 1);
                    int2 p;
                    p.x = cols[e] | (rl << 17);
                    p.y = __float_as_int(vals[e]);
                    staging[(long)bkt * CAP + dst] = p;
                }
            }
        }
        return;
    }

    // ----------------- gemm role -----------------
    const int g = blockIdx.x - NPB;
    const int wave = tid >> 6;
    const int lane = tid & 63;
    const int m16 = lane & 15;
    const int quad = lane >> 4;

    // stage preconverted W into LDS: 128 rows x 16 uint4 (32 KB), no conversion
    for (int i = tid; i < 128 * 16; i += 256) {
        int o = i >> 4;
        int k8 = (i & 15) * 8;
        *(uint4*)&sm.wb[o * WB_STRIDE + k8] = *(const uint4*)&Wbf[o * D_C + k8];
    }

    const int row0 = g * 64 + wave * 16;
    int row = row0 + m16;
    int rowc = (row < n) ? row : (n - 1);

    // load + convert this thread's A fragments (16 rows x 128 cols per wave)
    FragU a[4];
    const float* xp = X + (long)rowc * D_C + quad * 8;
#pragma unroll
    for (int s = 0; s < 4; ++s) {
        float4 x0 = *(const float4*)(xp + s * 32);
        float4 x1 = *(const float4*)(xp + s * 32 + 4);
        a[s].u.x = (unsigned)f2bf(x0.x) | ((unsigned)f2bf(x0.y) << 16);
        a[s].u.y = (unsigned)f2bf(x0.z) | ((unsigned)f2bf(x0.w) << 16);
        a[s].u.z = (unsigned)f2bf(x1.x) | ((unsigned)f2bf(x1.y) << 16);
        a[s].u.w = (unsigned)f2bf(x1.z) | ((unsigned)f2bf(x1.w) << 16);
    }
    __syncthreads();

    f32x4 acc[8];
#pragma unroll
    for (int t = 0; t < 8; ++t) acc[t] = (f32x4){0.f, 0.f, 0.f, 0.f};

#pragma unroll
    for (int s = 0; s < 4; ++s) {
#pragma unroll
        for (int t = 0; t < 8; ++t) {
            FragU bf;
            bf.u = *(const uint4*)&sm.wb[(t * 16 + m16) * WB_STRIDE + s * 32 + quad * 8];
            acc[t] = __builtin_amdgcn_mfma_f32_16x16x32_bf16(a[s].b, bf.b, acc[t], 0, 0, 0);
        }
    }

    // all waves done reading W tile -> reuse LDS as per-wave Y transpose tile
    __syncthreads();
    unsigned short* yt = sm.wb + wave * (16 * WB_STRIDE);
#pragma unroll
    for (int t = 0; t < 8; ++t)
#pragma unroll
        for (int r = 0; r < 4; ++r)
            yt[(quad * 4 + r) * WB_STRIDE + t * 16 + m16] = f2bf(acc[t][r]);
    __syncthreads();

    // each lane moves 16 elems (2 x uint4); 8 lanes cover a 128-elem row
#pragma unroll
    for (int h = 0; h < 2; ++h) {
        int row_l = h * 8 + (lane >> 3);
        int orow = row0 + row_l;
        if (orow < n) {
            const unsigned short* src = &yt[row_l * WB_STRIDE + (lane & 7) * 16];
            uint4 v0 = *(const uint4*)(src);
            uint4 v1 = *(const uint4*)(src + 8);
            uint4* dst = (uint4*)&Y[(long)orow * D_C + (lane & 7) * 16];
            dst[0] = v0;
            dst[1] = v1;
        }
    }
}

// ---------------------------------------------------------------------------
// K2 (sort+aggregate, full bucket — round-2 measured-best config, 72.5 us):
// one block per bucket; counting-sort the bucket span into LDS row-grouped,
// then 16-lane/row register-accumulating gather of Y rows, unroll-8.
// ---------------------------------------------------------------------------
__global__ __launch_bounds__(256) void sort_aggregate(const int* __restrict__ gcount,
                                                      const int2* __restrict__ staging,
                                                      const unsigned short* __restrict__ Y,
                                                      const float* __restrict__ bias,
                                                      float* __restrict__ out, int n) {
    __shared__ int2 pl[CAP];       // 12,288 B row-sorted payload
    __shared__ int hist[RPB];
    __shared__ int lcur[RPB];
    __shared__ int rbegL[RPB];
    __shared__ int rcntL[RPB];

    const int bb = blockIdx.x, tid = threadIdx.x;
    int cnt = gcount[bb];
    if (cnt > CAP) cnt = CAP;
    const long s = (long)bb * CAP;

    if (tid < RPB) hist[tid] = 0;
    __syncthreads();

    for (int i = tid; i < cnt; i += 256) {
        int rl = ((unsigned)staging[s + i].x) >> 17;
        atomicAdd(&hist[rl], 1);
    }
    __syncthreads();

    int v = (tid < RPB) ? hist[tid] : 0;
    // inclusive Hillis-Steele over RPB entries
    for (int off = 1; off < RPB; off <<= 1) {
        int t = (tid >= off && tid < RPB) ? hist[tid - off] : 0;
        __syncthreads();
        if (tid < RPB) hist[tid] += t;
        __syncthreads();
    }
    if (tid < RPB) {
        int excl = hist[tid] - v;
        lcur[tid] = excl;
        rbegL[tid] = excl;
        rcntL[tid] = v;
    }
    __syncthreads();

    for (int i = tid; i < cnt; i += 256) {
        int2 p = staging[s + i];
        int rl = ((unsigned)p.x) >> 17;
        int slot = atomicAdd(&lcur[rl], 1);
        pl[slot] = p;
    }
    __syncthreads();

    const int lane = tid & 15;
    const unsigned short* Yl = Y + lane * 8;
    float4 b0 = *(const float4*)&bias[lane * 8];
    float4 b1 = *(const float4*)&bias[lane * 8 + 4];

#pragma unroll
    for (int pass = 0; pass < RPB / 16; ++pass) {
        int rlocal = pass * 16 + (tid >> 4);
        int row = bb * RPB + rlocal;
        if (row >= n) continue;

        int i = rbegL[rlocal];
        int e = i + rcntL[rlocal];

        float acc[8];
        acc[0] = b0.x; acc[1] = b0.y; acc[2] = b0.z; acc[3] = b0.w;
        acc[4] = b1.x; acc[5] = b1.y; acc[6] = b1.z; acc[7] = b1.w;

        for (; i + 8 <= e; i += 8) {  // 8 independent 256B gathers in flight
            int2 p[8];
            uint4 y[8];
#pragma unroll
            for (int u = 0; u < 8; ++u) p[u] = pl[i + u];
#pragma unroll
            for (int u = 0; u < 8; ++u)
                y[u] = *(const uint4*)&Yl[(long)(p[u].x & 0x1FFFF) * D_C];
#pragma unroll
            for (int u = 0; u < 8; ++u) {
                float v2 = __int_as_float(p[u].y);
                acc[0] += v2 * bflo(y[u].x); acc[1] += v2 * bfhi(y[u].x);
                acc[2] += v2 * bflo(y[u].y); acc[3] += v2 * bfhi(y[u].y);
                acc[4] += v2 * bflo(y[u].z); acc[5] += v2 * bfhi(y[u].z);
                acc[6] += v2 * bflo(y[u].w); acc[7] += v2 * bfhi(y[u].w);
            }
        }
        for (; i + 4 <= e; i += 4) {
            int2 p[4];
            uint4 y[4];
#pragma unroll
            for (int u = 0; u < 4; ++u) p[u] = pl[i + u];
#pragma unroll
            for (int u = 0; u < 4; ++u)
                y[u] = *(const uint4*)&Yl[(long)(p[u].x & 0x1FFFF) * D_C];
#pragma unroll
            for (int u = 0; u < 4; ++u) {
                float v2 = __int_as_float(p[u].y);
                acc[0] += v2 * bflo(y[u].x); acc[1] += v2 * bfhi(y[u].x);
                acc[2] += v2 * bflo(y[u].y); acc[3] += v2 * bfhi(y[u].y);
                acc[4] += v2 * bflo(y[u].z); acc[5] += v2 * bfhi(y[u].z);
                acc[6] += v2 * bflo(y[u].w); acc[7] += v2 * bfhi(y[u].w);
            }
        }
        for (; i < e; ++i) {
            int2 p = pl[i];
            uint4 y = *(const uint4*)&Yl[(long)(p.x & 0x1FFFF) * D_C];
            float v2 = __int_as_float(p.y);
            acc[0] += v2 * bflo(y.x); acc[1] += v2 * bfhi(y.x);
            acc[2] += v2 * bflo(y.y); acc[3] += v2 * bfhi(y.y);
            acc[4] += v2 * bflo(y.z); acc[5] += v2 * bfhi(y.z);
            acc[6] += v2 * bflo(y.w); acc[7] += v2 * bfhi(y.w);
        }

        f32x4 o0 = {acc[0], acc[1], acc[2], acc[3]};
        f32x4 o1 = {acc[4], acc[5], acc[6], acc[7]};
        f32x4* op = (f32x4*)&out[(long)row * D_C + lane * 8];
        // out is write-once dead data: keep it out of L2/L3 so Y stays hot
        __builtin_nontemporal_store(o0, op);
        __builtin_nontemporal_store(o1, op + 1);
    }
}

// ---------------------------------------------------------------------------
// Fallback path (ws too small): standalone gemm + atomic scatter.
// ---------------------------------------------------------------------------
__global__ __launch_bounds__(256) void gemm_mfma(const float* __restrict__ X,
                                                 const float* __restrict__ W,
                                                 unsigned short* __restrict__ Y, int n) {
    __shared__ unsigned short Wb[128 * WB_STRIDE];

    const int tid = threadIdx.x;
    const int wave = tid >> 6;
    const int lane = tid & 63;
    const int m16 = lane & 15;
    const int quad = lane >> 4;

    const int row0 = blockIdx.x * 64 + wave * 16;
    int row = row0 + m16;
    int rowc = (row < n) ? row : (n - 1);

    float4 xv[4][2];
    const float* xp = X + (long)rowc * D_C + quad * 8;
#pragma unroll
    for (int s = 0; s < 4; ++s) {
        xv[s][0] = *(const float4*)(xp + s * 32);
        xv[s][1] = *(const float4*)(xp + s * 32 + 4);
    }

    for (int i = tid; i < 128 * 32; i += 256) {
        int o = i >> 5;
        int k4 = (i & 31) * 4;
        float4 w = *(const float4*)&W[o * 128 + k4];
        uint2 p;
        p.x = (unsigned)f2bf(w.x) | ((unsigned)f2bf(w.y) << 16);
        p.y = (unsigned)f2bf(w.z) | ((unsigned)f2bf(w.w) << 16);
        *(uint2*)&Wb[o * WB_STRIDE + k4] = p;
    }
    __syncthreads();

    FragU a[4];
#pragma unroll
    for (int s = 0; s < 4; ++s) {
        a[s].u.x = (unsigned)f2bf(xv[s][0].x) | ((unsigned)f2bf(xv[s][0].y) << 16);
        a[s].u.y = (unsigned)f2bf(xv[s][0].z) | ((unsigned)f2bf(xv[s][0].w) << 16);
        a[s].u.z = (unsigned)f2bf(xv[s][1].x) | ((unsigned)f2bf(xv[s][1].y) << 16);
        a[s].u.w = (unsigned)f2bf(xv[s][1].z) | ((unsigned)f2bf(xv[s][1].w) << 16);
    }

    f32x4 acc[8];
#pragma unroll
    for (int t = 0; t < 8; ++t) acc[t] = (f32x4){0.f, 0.f, 0.f, 0.f};

#pragma unroll
    for (int s = 0; s < 4; ++s) {
#pragma unroll
        for (int t = 0; t < 8; ++t) {
            FragU bf;
            bf.u = *(const uint4*)&Wb[(t * 16 + m16) * WB_STRIDE + s * 32 + quad * 8];
            acc[t] = __builtin_amdgcn_mfma_f32_16x16x32_bf16(a[s].b, bf.b, acc[t], 0, 0, 0);
        }
    }

#pragma unroll
    for (int t = 0; t < 8; ++t) {
#pragma unroll
        for (int r = 0; r < 4; ++r) {
            int orow = row0 + quad * 4 + r;
            if (orow < n) Y[(long)orow * D_C + t * 16 + m16] = f2bf(acc[t][r]);
        }
    }
}

__global__ __launch_bounds__(256) void init_out(const float* __restrict__ b,
                                                float* __restrict__ out, int n) {
    int idx = blockIdx.x * 256 + threadIdx.x;
    int total = n * (D_C / 4);
    if (idx < total) {
        int o4 = idx & (D_C / 4 - 1);
        ((float4*)out)[idx] = ((const float4*)b)[o4];
    }
}

__global__ __launch_bounds__(256) void scatter_edges(const int* __restrict__ rows,
                                                     const int* __restrict__ cols,
                                                     const float* __restrict__ vals,
                                                     const unsigned short* __restrict__ Y,
                                                     float* __restrict__ out, int E) {
    int e = blockIdx.x * 8 + (threadIdx.x >> 5);
    if (e >= E) return;
    int lane = threadIdx.x & 31;
    int row = rows[e];
    int col = cols[e];
    float v = vals[e];
    uint2 y = *(const uint2*)&Y[(long)col * D_C + lane * 4];
    float* dst = out + (long)row * D_C + lane * 4;
    unsafeAtomicAdd(dst + 0, v * bflo(y.x));
    unsafeAtomicAdd(dst + 1, v * bfhi(y.x));
    unsafeAtomicAdd(dst + 2, v * bflo(y.y));
    unsafeAtomicAdd(dst + 3, v * bfhi(y.y));
}

extern "C" void kernel_launch(void* const* d_in, const int* in_sizes, int n_in,
                              void* d_out, int out_size, void* d_ws, size_t ws_size,
                              hipStream_t stream) {
    const float* X  = (const float*)d_in[0];
    const int*   Ar = (const int*)d_in[1];
    const int*   Ac = (const int*)d_in[2];
    const float* Av = (const float*)d_in[3];
    const float* W  = (const float*)d_in[4];
    const float* b  = (const float*)d_in[5];
    float* out = (float*)d_out;

    // Workspace layout:
    unsigned short* Y = (unsigned short*)d_ws;              // 25.6 MB
    int2* staging = (int2*)(Y + 12800000);                  // 19.2 MB
    unsigned short* Wbf = (unsigned short*)(staging + (size_t)NBKT * CAP);  // 32 KB
    int* gcount = (int*)(Wbf + 16384);                      // 6.25 KB
    size_t need = (size_t)12800000 * 2 + (size_t)NBKT * CAP * 8 + 32768 + (size_t)NBKT * 4;

    if (ws_size >= need) {
        prep<<<23, 256, 0, stream>>>(W, Wbf, gcount);
        fused<<<NPB + NGB, 256, 0, stream>>>(X, Ar, Ac, Av, Wbf, gcount, staging, Y,
                                             N_NODES_C, N_EDGES_C);
        sort_aggregate<<<NBKT, 256, 0, stream>>>(gcount, staging, Y, b, out, N_NODES_C);
    } else {
        // Fallback: standalone gemm + atomic scatter
        gemm_mfma<<<(N_NODES_C + 63) / 64, 256, 0, stream>>>(X, W, Y, N_NODES_C);
        init_out<<<(N_NODES_C * (D_C / 4) + 255) / 256, 256, 0, stream>>>(b, out, N_NODES_C);
        scatter_edges<<<(N_EDGES_C + 7) / 8, 256, 0, stream>>>(Ar, Ac, Av, Y, out, N_EDGES_C);
    }
}

// Round 8
// 219.413 us; speedup vs baseline: 1.8795x; 1.0304x over previous
//
#include <hip/hip_runtime.h>

#define N_NODES_C 100000
#define N_EDGES_C 1600000
#define D_C 128
#define NBKT 1563        // ceil(100000/64) buckets of 64 rows
#define RPB 64           // rows per bucket (shift-based bucketing)
#define CAP 1536         // per-bucket edge capacity (mean 1024, sigma 32 -> +16 sigma)
#define PTILE 4096       // edges per partition block
#define NPB ((N_EDGES_C + PTILE - 1) / PTILE)     // 391 partition blocks
#define NGB ((N_NODES_C + 63) / 64)               // 1563 gemm blocks
#define WB_STRIDE 136    // padded row stride (elems) for LDS W tile

// bf16 helpers (manual RNE pack; unpack is exact)
static __device__ __forceinline__ unsigned short f2bf(float x) {
    unsigned u = __float_as_uint(x);
    unsigned r = 0x7fffu + ((u >> 16) & 1u);
    return (unsigned short)((u + r) >> 16);
}
static __device__ __forceinline__ float bflo(unsigned u) { return __uint_as_float(u << 16); }
static __device__ __forceinline__ float bfhi(unsigned u) { return __uint_as_float(u & 0xffff0000u); }

typedef __attribute__((ext_vector_type(8))) __bf16 bf16x8;
typedef __attribute__((ext_vector_type(4))) float f32x4;
union FragU { uint4 u; bf16x8 b; };

// ---------------------------------------------------------------------------
// K0 (prep): W f32 -> bf16 once; zero gcount; permuted bias for tiled-Y path.
// pbias[l*8 + j] = b[j*16 + l]  (lane l's j-th accumulator's bias)
// ---------------------------------------------------------------------------
__global__ __launch_bounds__(256) void prep(const float* __restrict__ W,
                                            const float* __restrict__ b,
                                            unsigned short* __restrict__ Wbf,
                                            int* __restrict__ gcount,
                                            float* __restrict__ pbias) {
    int t = blockIdx.x * 256 + threadIdx.x;
    if (t < 4096) {
        float4 w = ((const float4*)W)[t];
        uint2 p;
        p.x = (unsigned)f2bf(w.x) | ((unsigned)f2bf(w.y) << 16);
        p.y = (unsigned)f2bf(w.z) | ((unsigned)f2bf(w.w) << 16);
        ((uint2*)Wbf)[t] = p;
    } else if (t < 4096 + NBKT) {
        gcount[t - 4096] = 0;
    } else {
        int k = t - (4096 + NBKT);
        if (k < 128) pbias[k] = b[(k & 7) * 16 + (k >> 3)];
    }
}

// ---------------------------------------------------------------------------
// K1 (fused): role-split grid. blockIdx < NPB -> edge partition; else GEMM.
//
// GEMM role: Y' = bf16(X @ W^T) in TILED row layout:
//   Y'[row][m16*8 + t] = Yorig[row][t*16 + m16]   (m16 in [0,16), t in [0,8))
// This matches the MFMA C-fragment exactly: each thread packs acc[0..7][r]
// into one uint4 and stores 16 B directly -> no LDS transpose, no extra syncs.
// The aggregate kernel reads the same 16 B/lane chunks as before; only the
// element meaning changes (compensated via pbias + out-store addressing).
// ---------------------------------------------------------------------------
union SMemF {
    struct {
        int lhist[NBKT];
        int lbase[NBKT];
        unsigned short ebkt[PTILE];
        unsigned short ernk[PTILE];
    } part;                              // 28,888 B
    unsigned short wb[128 * WB_STRIDE];  // 34,816 B (bf16 W tile)
};

__global__ __launch_bounds__(256) void fused(const float* __restrict__ X,
                                             const int* __restrict__ rows,
                                             const int* __restrict__ cols,
                                             const float* __restrict__ vals,
                                             const unsigned short* __restrict__ Wbf,
                                             int* __restrict__ gcount,
                                             int2* __restrict__ staging,
                                             unsigned short* __restrict__ Y,
                                             int n, int E) {
    __shared__ SMemF sm;
    const int tid = threadIdx.x;

    if (blockIdx.x < NPB) {
        // ----------------- partition role -----------------
        const int t0 = blockIdx.x * PTILE;

        for (int i = tid; i < NBKT; i += 256) sm.part.lhist[i] = 0;
        __syncthreads();

#pragma unroll
        for (int k = 0; k < PTILE / 256; ++k) {
            int e = t0 + k * 256 + tid;
            if (e < E) {
                int bkt = rows[e] >> 6;
                int rnk = atomicAdd(&sm.part.lhist[bkt], 1);
                sm.part.ebkt[k * 256 + tid] = (unsigned short)bkt;
                sm.part.ernk[k * 256 + tid] = (unsigned short)rnk;
            }
        }
        __syncthreads();

        for (int i = tid; i < NBKT; i += 256)
            sm.part.lbase[i] = sm.part.lhist[i] ? atomicAdd(&gcount[i], sm.part.lhist[i]) : 0;
        __syncthreads();

#pragma unroll
        for (int k = 0; k < PTILE / 256; ++k) {
            int e = t0 + k * 256 + tid;
            if (e < E) {
                int li = k * 256 + tid;
                int bkt = sm.part.ebkt[li];
                int dst = sm.part.lbase[bkt] + sm.part.ernk[li];
                if (dst < CAP) {
                    int rl = rows[e] & (RPB - 1);
                    int2 p;
                    p.x = cols[e] | (rl << 17);
                    p.y = __float_as_int(vals[e]);
                    staging[(long)bkt * CAP + dst] = p;
                }
            }
        }
        return;
    }

    // ----------------- gemm role -----------------
    const int g = blockIdx.x - NPB;
    const int wave = tid >> 6;
    const int lane = tid & 63;
    const int m16 = lane & 15;
    const int quad = lane >> 4;

    // stage preconverted W into LDS: 128 rows x 16 uint4 (32 KB).
    // uint4 = 16 B = 8 bf16 elems -> 16 copies per 128-elem row.
    for (int i = tid; i < 128 * 16; i += 256) {
        int o = i >> 4;
        int k8 = (i & 15) * 8;
        *(uint4*)&sm.wb[o * WB_STRIDE + k8] = *(const uint4*)&Wbf[o * D_C + k8];
    }

    const int row0 = g * 64 + wave * 16;
    int row = row0 + m16;
    int rowc = (row < n) ? row : (n - 1);

    // load + convert this thread's A fragments (16 rows x 128 cols per wave)
    FragU a[4];
    const float* xp = X + (long)rowc * D_C + quad * 8;
#pragma unroll
    for (int s = 0; s < 4; ++s) {
        float4 x0 = *(const float4*)(xp + s * 32);
        float4 x1 = *(const float4*)(xp + s * 32 + 4);
        a[s].u.x = (unsigned)f2bf(x0.x) | ((unsigned)f2bf(x0.y) << 16);
        a[s].u.y = (unsigned)f2bf(x0.z) | ((unsigned)f2bf(x0.w) << 16);
        a[s].u.z = (unsigned)f2bf(x1.x) | ((unsigned)f2bf(x1.y) << 16);
        a[s].u.w = (unsigned)f2bf(x1.z) | ((unsigned)f2bf(x1.w) << 16);
    }
    __syncthreads();

    f32x4 acc[8];
#pragma unroll
    for (int t = 0; t < 8; ++t) acc[t] = (f32x4){0.f, 0.f, 0.f, 0.f};

#pragma unroll
    for (int s = 0; s < 4; ++s) {
#pragma unroll
        for (int t = 0; t < 8; ++t) {
            FragU bf;
            bf.u = *(const uint4*)&sm.wb[(t * 16 + m16) * WB_STRIDE + s * 32 + quad * 8];
            acc[t] = __builtin_amdgcn_mfma_f32_16x16x32_bf16(a[s].b, bf.b, acc[t], 0, 0, 0);
        }
    }

    // direct tiled-layout stores: Y'[row][m16*8 + t] = acc[t][r]
    // (one uint4 = 8 bf16 per owned row; 16 lanes cover the 256-B row)
#pragma unroll
    for (int r = 0; r < 4; ++r) {
        int orow = row0 + quad * 4 + r;
        if (orow < n) {
            uint4 v;
            v.x = (unsigned)f2bf(acc[0][r]) | ((unsigned)f2bf(acc[1][r]) << 16);
            v.y = (unsigned)f2bf(acc[2][r]) | ((unsigned)f2bf(acc[3][r]) << 16);
            v.z = (unsigned)f2bf(acc[4][r]) | ((unsigned)f2bf(acc[5][r]) << 16);
            v.w = (unsigned)f2bf(acc[6][r]) | ((unsigned)f2bf(acc[7][r]) << 16);
            *(uint4*)&Y[(long)orow * D_C + m16 * 8] = v;
        }
    }
}

// ---------------------------------------------------------------------------
// K2 (sort+aggregate): one block per bucket. The bucket span (<=1536 = 6
// int2/thread) is held in REGISTERS -> staging read once (was twice).
// Gather: 16 lanes/row, 16 B/lane from tiled Y'; lane l's j-th accumulator
// is orig column j*16+l (bias via pbias; out store at j*16+l).
// ---------------------------------------------------------------------------
__global__ __launch_bounds__(256) void sort_aggregate(const int* __restrict__ gcount,
                                                      const int2* __restrict__ staging,
                                                      const unsigned short* __restrict__ Y,
                                                      const float* __restrict__ pbias,
                                                      float* __restrict__ out, int n) {
    __shared__ int2 pl[CAP];       // 12,288 B row-sorted payload
    __shared__ int hist[RPB];
    __shared__ int lcur[RPB];
    __shared__ int rbegL[RPB];
    __shared__ int rcntL[RPB];

    const int bb = blockIdx.x, tid = threadIdx.x;
    int cnt = gcount[bb];
    if (cnt > CAP) cnt = CAP;
    const long s = (long)bb * CAP;

    if (tid < RPB) hist[tid] = 0;
    __syncthreads();

    // load bucket span into registers (static indexing; 6*256 = CAP exactly)
    int2 p_reg[6];
#pragma unroll
    for (int k = 0; k < 6; ++k) {
        int i = k * 256 + tid;
        if (i < cnt) p_reg[k] = staging[s + i];
    }
#pragma unroll
    for (int k = 0; k < 6; ++k) {
        int i = k * 256 + tid;
        if (i < cnt) atomicAdd(&hist[((unsigned)p_reg[k].x) >> 17], 1);
    }
    __syncthreads();

    int v = (tid < RPB) ? hist[tid] : 0;
    // inclusive Hillis-Steele over RPB entries
    for (int off = 1; off < RPB; off <<= 1) {
        int t = (tid >= off && tid < RPB) ? hist[tid - off] : 0;
        __syncthreads();
        if (tid < RPB) hist[tid] += t;
        __syncthreads();
    }
    if (tid < RPB) {
        int excl = hist[tid] - v;
        lcur[tid] = excl;
        rbegL[tid] = excl;
        rcntL[tid] = v;
    }
    __syncthreads();

#pragma unroll
    for (int k = 0; k < 6; ++k) {
        int i = k * 256 + tid;
        if (i < cnt) {
            int rl = ((unsigned)p_reg[k].x) >> 17;
            int slot = atomicAdd(&lcur[rl], 1);
            pl[slot] = p_reg[k];
        }
    }
    __syncthreads();

    const int lane = tid & 15;
    const unsigned short* Yl = Y + lane * 8;
    float4 b0 = *(const float4*)&pbias[lane * 8];
    float4 b1 = *(const float4*)&pbias[lane * 8 + 4];

#pragma unroll
    for (int pass = 0; pass < RPB / 16; ++pass) {
        int rlocal = pass * 16 + (tid >> 4);
        int row = bb * RPB + rlocal;
        if (row >= n) continue;

        int i = rbegL[rlocal];
        int e = i + rcntL[rlocal];

        float acc[8];
        acc[0] = b0.x; acc[1] = b0.y; acc[2] = b0.z; acc[3] = b0.w;
        acc[4] = b1.x; acc[5] = b1.y; acc[6] = b1.z; acc[7] = b1.w;

        for (; i + 8 <= e; i += 8) {  // 8 independent 256B gathers in flight
            int2 p[8];
            uint4 y[8];
#pragma unroll
            for (int u = 0; u < 8; ++u) p[u] = pl[i + u];
#pragma unroll
            for (int u = 0; u < 8; ++u)
                y[u] = *(const uint4*)&Yl[(long)(p[u].x & 0x1FFFF) * D_C];
#pragma unroll
            for (int u = 0; u < 8; ++u) {
                float v2 = __int_as_float(p[u].y);
                acc[0] += v2 * bflo(y[u].x); acc[1] += v2 * bfhi(y[u].x);
                acc[2] += v2 * bflo(y[u].y); acc[3] += v2 * bfhi(y[u].y);
                acc[4] += v2 * bflo(y[u].z); acc[5] += v2 * bfhi(y[u].z);
                acc[6] += v2 * bflo(y[u].w); acc[7] += v2 * bfhi(y[u].w);
            }
        }
        for (; i + 4 <= e; i += 4) {
            int2 p[4];
            uint4 y[4];
#pragma unroll
            for (int u = 0; u < 4; ++u) p[u] = pl[i + u];
#pragma unroll
            for (int u = 0; u < 4; ++u)
                y[u] = *(const uint4*)&Yl[(long)(p[u].x & 0x1FFFF) * D_C];
#pragma unroll
            for (int u = 0; u < 4; ++u) {
                float v2 = __int_as_float(p[u].y);
                acc[0] += v2 * bflo(y[u].x); acc[1] += v2 * bfhi(y[u].x);
                acc[2] += v2 * bflo(y[u].y); acc[3] += v2 * bfhi(y[u].y);
                acc[4] += v2 * bflo(y[u].z); acc[5] += v2 * bfhi(y[u].z);
                acc[6] += v2 * bflo(y[u].w); acc[7] += v2 * bfhi(y[u].w);
            }
        }
        for (; i < e; ++i) {
            int2 p = pl[i];
            uint4 y = *(const uint4*)&Yl[(long)(p.x & 0x1FFFF) * D_C];
            float v2 = __int_as_float(p.y);
            acc[0] += v2 * bflo(y.x); acc[1] += v2 * bfhi(y.x);
            acc[2] += v2 * bflo(y.y); acc[3] += v2 * bfhi(y.y);
            acc[4] += v2 * bflo(y.z); acc[5] += v2 * bfhi(y.z);
            acc[6] += v2 * bflo(y.w); acc[7] += v2 * bfhi(y.w);
        }

        // acc[j] belongs to orig column j*16+lane; consecutive lanes give
        // contiguous 64-B segments per j -> coalesced nontemporal dwords.
        float* op = out + (long)row * D_C + lane;
#pragma unroll
        for (int j = 0; j < 8; ++j)
            __builtin_nontemporal_store(acc[j], op + j * 16);
    }
}

// ---------------------------------------------------------------------------
// Fallback path (ws too small): standalone gemm + atomic scatter.
// (Self-consistent: original row-major Y layout throughout.)
// ---------------------------------------------------------------------------
__global__ __launch_bounds__(256) void gemm_mfma(const float* __restrict__ X,
                                                 const float* __restrict__ W,
                                                 unsigned short* __restrict__ Y, int n) {
    __shared__ unsigned short Wb[128 * WB_STRIDE];

    const int tid = threadIdx.x;
    const int wave = tid >> 6;
    const int lane = tid & 63;
    const int m16 = lane & 15;
    const int quad = lane >> 4;

    const int row0 = blockIdx.x * 64 + wave * 16;
    int row = row0 + m16;
    int rowc = (row < n) ? row : (n - 1);

    float4 xv[4][2];
    const float* xp = X + (long)rowc * D_C + quad * 8;
#pragma unroll
    for (int s = 0; s < 4; ++s) {
        xv[s][0] = *(const float4*)(xp + s * 32);
        xv[s][1] = *(const float4*)(xp + s * 32 + 4);
    }

    for (int i = tid; i < 128 * 32; i += 256) {
        int o = i >> 5;
        int k4 = (i & 31) * 4;
        float4 w = *(const float4*)&W[o * 128 + k4];
        uint2 p;
        p.x = (unsigned)f2bf(w.x) | ((unsigned)f2bf(w.y) << 16);
        p.y = (unsigned)f2bf(w.z) | ((unsigned)f2bf(w.w) << 16);
        *(uint2*)&Wb[o * WB_STRIDE + k4] = p;
    }
    __syncthreads();

    FragU a[4];
#pragma unroll
    for (int s = 0; s < 4; ++s) {
        a[s].u.x = (unsigned)f2bf(xv[s][0].x) | ((unsigned)f2bf(xv[s][0].y) << 16);
        a[s].u.y = (unsigned)f2bf(xv[s][0].z) | ((unsigned)f2bf(xv[s][0].w) << 16);
        a[s].u.z = (unsigned)f2bf(xv[s][1].x) | ((unsigned)f2bf(xv[s][1].y) << 16);
        a[s].u.w = (unsigned)f2bf(xv[s][1].z) | ((unsigned)f2bf(xv[s][1].w) << 16);
    }

    f32x4 acc[8];
#pragma unroll
    for (int t = 0; t < 8; ++t) acc[t] = (f32x4){0.f, 0.f, 0.f, 0.f};

#pragma unroll
    for (int s = 0; s < 4; ++s) {
#pragma unroll
        for (int t = 0; t < 8; ++t) {
            FragU bf;
            bf.u = *(const uint4*)&Wb[(t * 16 + m16) * WB_STRIDE + s * 32 + quad * 8];
            acc[t] = __builtin_amdgcn_mfma_f32_16x16x32_bf16(a[s].b, bf.b, acc[t], 0, 0, 0);
        }
    }

#pragma unroll
    for (int t = 0; t < 8; ++t) {
#pragma unroll
        for (int r = 0; r < 4; ++r) {
            int orow = row0 + quad * 4 + r;
            if (orow < n) Y[(long)orow * D_C + t * 16 + m16] = f2bf(acc[t][r]);
        }
    }
}

__global__ __launch_bounds__(256) void init_out(const float* __restrict__ b,
                                                float* __restrict__ out, int n) {
    int idx = blockIdx.x * 256 + threadIdx.x;
    int total = n * (D_C / 4);
    if (idx < total) {
        int o4 = idx & (D_C / 4 - 1);
        ((float4*)out)[idx] = ((const float4*)b)[o4];
    }
}

__global__ __launch_bounds__(256) void scatter_edges(const int* __restrict__ rows,
                                                     const int* __restrict__ cols,
                                                     const float* __restrict__ vals,
                                                     const unsigned short* __restrict__ Y,
                                                     float* __restrict__ out, int E) {
    int e = blockIdx.x * 8 + (threadIdx.x >> 5);
    if (e >= E) return;
    int lane = threadIdx.x & 31;
    int row = rows[e];
    int col = cols[e];
    float v = vals[e];
    uint2 y = *(const uint2*)&Y[(long)col * D_C + lane * 4];
    float* dst = out + (long)row * D_C + lane * 4;
    unsafeAtomicAdd(dst + 0, v * bflo(y.x));
    unsafeAtomicAdd(dst + 1, v * bfhi(y.x));
    unsafeAtomicAdd(dst + 2, v * bflo(y.y));
    unsafeAtomicAdd(dst + 3, v * bfhi(y.y));
}

extern "C" void kernel_launch(void* const* d_in, const int* in_sizes, int n_in,
                              void* d_out, int out_size, void* d_ws, size_t ws_size,
                              hipStream_t stream) {
    const float* X  = (const float*)d_in[0];
    const int*   Ar = (const int*)d_in[1];
    const int*   Ac = (const int*)d_in[2];
    const float* Av = (const float*)d_in[3];
    const float* W  = (const float*)d_in[4];
    const float* b  = (const float*)d_in[5];
    float* out = (float*)d_out;

    // Workspace layout:
    unsigned short* Y = (unsigned short*)d_ws;              // 25.6 MB
    int2* staging = (int2*)(Y + 12800000);                  // 19.2 MB
    unsigned short* Wbf = (unsigned short*)(staging + (size_t)NBKT * CAP);  // 32 KB
    int* gcount = (int*)(Wbf + 16384);                      // 6.25 KB
    float* pbias = (float*)(gcount + NBKT);                 // 512 B
    size_t need = (size_t)12800000 * 2 + (size_t)NBKT * CAP * 8 + 32768 +
                  (size_t)NBKT * 4 + 512;

    if (ws_size >= need) {
        prep<<<23, 256, 0, stream>>>(W, b, Wbf, gcount, pbias);
        fused<<<NPB + NGB, 256, 0, stream>>>(X, Ar, Ac, Av, Wbf, gcount, staging, Y,
                                             N_NODES_C, N_EDGES_C);
        sort_aggregate<<<NBKT, 256, 0, stream>>>(gcount, staging, Y, pbias, out, N_NODES_C);
    } else {
        // Fallback: standalone gemm + atomic scatter
        gemm_mfma<<<(N_NODES_C + 63) / 64, 256, 0, stream>>>(X, W, Y, N_NODES_C);
        init_out<<<(N_NODES_C * (D_C / 4) + 255) / 256, 256, 0, stream>>>(b, out, N_NODES_C);
        scatter_edges<<<(N_EDGES_C + 7) / 8, 256, 0, stream>>>(Ar, Ac, Av, Y, out, N_EDGES_C);
    }
}